// Round 1
// baseline (5568.203 us; speedup 1.0000x reference)
//
#include <hip/hip_runtime.h>
#include <math.h>

// Problem constants (fixed by the reference)
#define CS  1024   // seq len (qlen == klen)
#define CB  2      // batch
#define CD  1024   // d_model
#define CN  16     // n_head
#define CDH 64     // d_head
#define CDI 4096   // d_inner
#define CR  2048   // rel pos emb length (2*S)
#define CL  2      // layers

// ---------------------------------------------------------------------------
// Generic fp32 tiled GEMM: C[M,N] = A[M,K] @ B  (+bias) (+gelu) (+res)
//   BT=false: B is [K,N] row-major.  BT=true: B is [N,K] row-major (A@B^T).
// Tile 128x128x8, 256 threads, 8x8 per-thread microtile.
// ---------------------------------------------------------------------------
template<bool BT, bool GELU>
__global__ __launch_bounds__(256) void gemm_kernel(
    const float* __restrict__ A, const float* __restrict__ B,
    float* __restrict__ C, int M, int N, int K,
    const float* __restrict__ bias, const float* __restrict__ res)
{
    __shared__ float As[8][128];   // [k][m]
    __shared__ float Bs[8][128];   // [k][n]
    const int tid = threadIdx.x;
    const int tx = tid & 15;       // n direction
    const int ty = tid >> 4;       // m direction
    const int m0 = blockIdx.y * 128;
    const int n0 = blockIdx.x * 128;

    float acc[8][8];
#pragma unroll
    for (int i = 0; i < 8; ++i)
#pragma unroll
        for (int j = 0; j < 8; ++j) acc[i][j] = 0.f;

    const int rA  = tid >> 1;          // 0..127
    const int cA  = (tid & 1) * 4;     // 0 or 4
    const int rBn = tid >> 5;          // 0..7  (k row, non-BT)
    const int cBn = (tid & 31) * 4;    // 0..124

    for (int k0 = 0; k0 < K; k0 += 8) {
        float4 av = *(const float4*)(A + (size_t)(m0 + rA) * K + (k0 + cA));
        As[cA + 0][rA] = av.x; As[cA + 1][rA] = av.y;
        As[cA + 2][rA] = av.z; As[cA + 3][rA] = av.w;
        if (!BT) {
            *(float4*)(&Bs[rBn][cBn]) =
                *(const float4*)(B + (size_t)(k0 + rBn) * N + (n0 + cBn));
        } else {
            float4 bv = *(const float4*)(B + (size_t)(n0 + rA) * K + (k0 + cA));
            Bs[cA + 0][rA] = bv.x; Bs[cA + 1][rA] = bv.y;
            Bs[cA + 2][rA] = bv.z; Bs[cA + 3][rA] = bv.w;
        }
        __syncthreads();
#pragma unroll
        for (int k = 0; k < 8; ++k) {
            float a[8], bb[8];
            *(float4*)&a[0]  = *(const float4*)&As[k][ty * 8];
            *(float4*)&a[4]  = *(const float4*)&As[k][ty * 8 + 4];
            *(float4*)&bb[0] = *(const float4*)&Bs[k][tx * 8];
            *(float4*)&bb[4] = *(const float4*)&Bs[k][tx * 8 + 4];
#pragma unroll
            for (int i = 0; i < 8; ++i)
#pragma unroll
                for (int j = 0; j < 8; ++j)
                    acc[i][j] = fmaf(a[i], bb[j], acc[i][j]);
        }
        __syncthreads();
    }

#pragma unroll
    for (int i = 0; i < 8; ++i) {
        const int row = m0 + ty * 8 + i;
#pragma unroll
        for (int j4 = 0; j4 < 8; j4 += 4) {
            const int col = n0 + tx * 8 + j4;
            float4 v = *(float4*)&acc[i][j4];
            if (bias) {
                const float4 bv = *(const float4*)(bias + col);
                v.x += bv.x; v.y += bv.y; v.z += bv.z; v.w += bv.w;
            }
            if (GELU) {
                v.x = 0.5f * v.x * (1.f + erff(v.x * 0.70710678118654752f));
                v.y = 0.5f * v.y * (1.f + erff(v.y * 0.70710678118654752f));
                v.z = 0.5f * v.z * (1.f + erff(v.z * 0.70710678118654752f));
                v.w = 0.5f * v.w * (1.f + erff(v.w * 0.70710678118654752f));
            }
            if (res) {
                const float4 rv = *(const float4*)(res + (size_t)row * N + col);
                v.x += rv.x; v.y += rv.y; v.z += rv.z; v.w += rv.w;
            }
            *(float4*)(C + (size_t)row * N + col) = v;
        }
    }
}

// ---------------------------------------------------------------------------
// Pack seg_mat[S,S,B,2] one-hot into byte array segb[b][i][j] = (seg differs)
// ---------------------------------------------------------------------------
__global__ __launch_bounds__(256) void segpack_kernel(
    const float* __restrict__ seg_mat, unsigned char* __restrict__ segb)
{
    const int idx = blockIdx.x * 256 + threadIdx.x;   // < S*S*B = 2M
    const int b   = idx / (CS * CS);
    const int rem = idx - b * (CS * CS);
    const int i   = rem >> 10;
    const int j   = rem & (CS - 1);
    segb[idx] = seg_mat[(((size_t)i * CS + j) * CB + b) * 2 + 1] > 0.5f ? 1 : 0;
}

// ---------------------------------------------------------------------------
// ef[s][i,b,n] = sum_d (qh[i,b,n,d] + r_s_bias[n,d]) * seg_embed[s,n,d]
// ---------------------------------------------------------------------------
__global__ __launch_bounds__(256) void ef_kernel(
    const float* __restrict__ qh, const float* __restrict__ rsb,
    const float* __restrict__ sege, float* __restrict__ ef)
{
    const int idx = blockIdx.x * 256 + threadIdx.x;   // < S*B*N = 32768
    const int n = idx & (CN - 1);
    const float* q  = qh + (size_t)idx * CDH;
    const float* sb = rsb + n * CDH;
    const float* s0 = sege + n * CDH;
    const float* s1 = sege + (CN + n) * CDH;
    float e0 = 0.f, e1 = 0.f;
#pragma unroll
    for (int d = 0; d < CDH; ++d) {
        const float qv = q[d] + sb[d];
        e0 = fmaf(qv, s0[d], e0);
        e1 = fmaf(qv, s1[d], e1);
    }
    ef[idx] = e0;
    ef[CS * CB * CN + idx] = e1;
}

// ---------------------------------------------------------------------------
// Relative attention. One block = 8 query rows for one (b, n).
// score[i,j] = ((q+rw)·k[j] + (q+rr)·kr[j+S-i] + ef_sel) * 1/8, causal.
// Scores staged in LDS, softmax, then PV.
// ---------------------------------------------------------------------------
__global__ __launch_bounds__(256) void attn_kernel(
    const float* __restrict__ qh, const float* __restrict__ kh,
    const float* __restrict__ vh, const float* __restrict__ kr,
    const float* __restrict__ ef, const unsigned char* __restrict__ segb,
    const float* __restrict__ rwb, const float* __restrict__ rrb,
    float* __restrict__ vec)
{
    __shared__ float sc[8][CS];        // 32 KB score rows
    __shared__ float kt[32 * 65];      // k / v tile, +65 stride: conflict-free
    __shared__ float krt[40 * 65];     // kr tile (TI+TJ-1=39 rows used)
    __shared__ float qrw[8][64];
    __shared__ float qrr[8][64];
    __shared__ float ef0s[8], ef1s[8], rinv[8];

    const int i0 = blockIdx.x * 8;
    const int b  = blockIdx.y >> 4;
    const int n  = blockIdx.y & 15;
    const int tid = threadIdx.x;
    const int r = tid >> 5;            // row within tile, 0..7
    const int c = tid & 31;            // 0..31

    // stage q (+ biases)
    for (int idx = tid; idx < 512; idx += 256) {
        const int rr = idx >> 6, d = idx & 63;
        const float qv = qh[(((size_t)(i0 + rr) * CB + b) * CN + n) * CDH + d];
        qrw[rr][d] = qv + rwb[n * CDH + d];
        qrr[rr][d] = qv + rrb[n * CDH + d];
    }
    if (tid < 8) {
        const size_t e = ((size_t)(i0 + tid) * CB + b) * CN + n;
        ef0s[tid] = ef[e];
        ef1s[tid] = ef[(size_t)CS * CB * CN + e];
    }
    __syncthreads();

    const int ntile = (i0 + 8 + 31) >> 5;   // ceil((i0+8)/32) j-tiles
    const int i = i0 + r;

    // ---- score phase ----
    for (int t = 0; t < ntile; ++t) {
        const int j0 = t << 5;
        for (int idx = tid; idx < 2048; idx += 256) {
            const int row = idx >> 6, d = idx & 63;
            kt[row * 65 + d] = kh[(((size_t)(j0 + row) * CB + b) * CN + n) * CDH + d];
        }
        const int gbase = j0 + CS - i0 - 7;   // always in [1, 1024]
        for (int idx = tid; idx < 2560; idx += 256) {
            const int row = idx >> 6, d = idx & 63;
            const int g = gbase + row;
            krt[row * 65 + d] = (g >= 0 && g < CR)
                ? kr[(((size_t)g * CB + b) * CN + n) * CDH + d] : 0.f;
        }
        __syncthreads();
        const int j = j0 + c;
        float s = -1e30f;
        if (j <= i) {
            const float* kk = &kt[c * 65];
            const float* kg = &krt[(c + 7 - r) * 65];   // kr row for g = j+S-i
            float s1 = 0.f, s2 = 0.f;
#pragma unroll
            for (int d = 0; d < 64; ++d) {
                s1 = fmaf(qrw[r][d], kk[d], s1);
                s2 = fmaf(qrr[r][d], kg[d], s2);
            }
            const float e = segb[((size_t)b * CS + i) * CS + j] ? ef1s[r] : ef0s[r];
            s = (s1 + s2 + e) * 0.125f;   // 1/sqrt(64)
        }
        sc[r][j] = s;
        __syncthreads();
    }

    // ---- softmax (32 lanes per row) ----
    const int JV = ntile << 5;
    float m = -1e30f;
    for (int jj = c; jj < JV; jj += 32) m = fmaxf(m, sc[r][jj]);
#pragma unroll
    for (int off = 16; off; off >>= 1) m = fmaxf(m, __shfl_xor(m, off, 32));
    float ssum = 0.f;
    for (int jj = c; jj < JV; jj += 32) {
        const float p = __expf(sc[r][jj] - m);
        sc[r][jj] = p;
        ssum += p;
    }
#pragma unroll
    for (int off = 16; off; off >>= 1) ssum += __shfl_xor(ssum, off, 32);
    if (c == 0) rinv[r] = 1.f / ssum;
    __syncthreads();

    // ---- PV phase ----
    float o0 = 0.f, o1 = 0.f;
    for (int t = 0; t < ntile; ++t) {
        const int j0 = t << 5;
        for (int idx = tid; idx < 2048; idx += 256) {
            const int row = idx >> 6, d = idx & 63;
            kt[row * 65 + d] = vh[(((size_t)(j0 + row) * CB + b) * CN + n) * CDH + d];
        }
        __syncthreads();
#pragma unroll
        for (int jj = 0; jj < 32; ++jj) {
            const float p = sc[r][j0 + jj];   // 0 for masked j
            o0 = fmaf(p, kt[jj * 65 + c], o0);
            o1 = fmaf(p, kt[jj * 65 + c + 32], o1);
        }
        __syncthreads();
    }
    const float ri = rinv[r];
    float* op = vec + (((size_t)i * CB + b) * CN + n) * CDH;
    op[c]      = o0 * ri;
    op[c + 32] = o1 * ri;
}

// ---------------------------------------------------------------------------
// LayerNorm over D=1024, one block per row (256 thr x float4)
// ---------------------------------------------------------------------------
__global__ __launch_bounds__(256) void ln_kernel(
    const float* __restrict__ x, float* __restrict__ y,
    const float* __restrict__ g, const float* __restrict__ bb)
{
    __shared__ float red[8];
    const int row = blockIdx.x;
    const int tid = threadIdx.x;
    const float4 v = ((const float4*)(x + (size_t)row * CD))[tid];
    float s = v.x + v.y + v.z + v.w;
#pragma unroll
    for (int off = 32; off; off >>= 1) s += __shfl_xor(s, off, 64);
    if ((tid & 63) == 0) red[tid >> 6] = s;
    __syncthreads();
    const float mean = (red[0] + red[1] + red[2] + red[3]) * (1.f / CD);
    const float d0 = v.x - mean, d1 = v.y - mean, d2 = v.z - mean, d3 = v.w - mean;
    float ss = d0 * d0 + d1 * d1 + d2 * d2 + d3 * d3;
#pragma unroll
    for (int off = 32; off; off >>= 1) ss += __shfl_xor(ss, off, 64);
    if ((tid & 63) == 0) red[4 + (tid >> 6)] = ss;
    __syncthreads();
    const float var  = (red[4] + red[5] + red[6] + red[7]) * (1.f / CD);
    const float rstd = rsqrtf(var + 1e-12f);
    const float4 gv = ((const float4*)g)[tid];
    const float4 bv = ((const float4*)bb)[tid];
    float4 o;
    o.x = d0 * rstd * gv.x + bv.x;
    o.y = d1 * rstd * gv.y + bv.y;
    o.z = d2 * rstd * gv.z + bv.z;
    o.w = d3 * rstd * gv.w + bv.w;
    ((float4*)(y + (size_t)row * CD))[tid] = o;
}

// ---------------------------------------------------------------------------
// Orchestration. Workspace layout (float offsets, 1M = 2^20):
//   cur 0-2M | qh 2-4M | kh 4-6M | vh 6-8M | kr 8-12M | vec 12-14M
//   ax 14-16M | x 16-18M | ef 18M-18M+64K | segb bytes after
//   ff (FFN intermediate, 8M floats) aliases 2-10M (qh..kr dead by then)
// Total ~75 MB.
// ---------------------------------------------------------------------------
extern "C" void kernel_launch(void* const* d_in, const int* in_sizes, int n_in,
                              void* d_out, int out_size, void* d_ws, size_t ws_size,
                              hipStream_t stream)
{
    const float* h       = (const float*)d_in[0];
    const float* pos_emb = (const float*)d_in[1];
    // d_in[2] attn_mask: fixed causal triu — hard-coded in attn_kernel
    const float* seg_mat = (const float*)d_in[3];
    const float* Wq  = (const float*)d_in[4];
    const float* Wk  = (const float*)d_in[5];
    const float* Wv  = (const float*)d_in[6];
    const float* Wo  = (const float*)d_in[7];
    const float* Wr  = (const float*)d_in[8];
    const float* rwb = (const float*)d_in[9];
    const float* rrb = (const float*)d_in[10];
    const float* rsb = (const float*)d_in[11];
    const float* sege = (const float*)d_in[12];
    const float* ln1g = (const float*)d_in[13];
    const float* ln1b = (const float*)d_in[14];
    const float* fw1  = (const float*)d_in[15];
    const float* fb1  = (const float*)d_in[16];
    const float* fw2  = (const float*)d_in[17];
    const float* fb2  = (const float*)d_in[18];
    const float* ln2g = (const float*)d_in[19];
    const float* ln2b = (const float*)d_in[20];
    float* out = (float*)d_out;
    float* ws  = (float*)d_ws;

    const size_t M1 = 1u << 20;
    float* cur = ws;
    float* qh  = ws + 2 * M1;
    float* kh  = ws + 4 * M1;
    float* vh  = ws + 6 * M1;
    float* krb = ws + 8 * M1;
    float* vec = ws + 12 * M1;
    float* ax  = ws + 14 * M1;
    float* xb  = ws + 16 * M1;
    float* ff  = ws + 2 * M1;               // alias: qh..kr dead when used
    float* efb = ws + 18 * M1;
    unsigned char* segb = (unsigned char*)(ws + 18 * M1 + 65536);

    hipMemcpyAsync(cur, h, (size_t)CS * CB * CD * sizeof(float),
                   hipMemcpyDeviceToDevice, stream);
    segpack_kernel<<<(CS * CS * CB) / 256, 256, 0, stream>>>(seg_mat, segb);

    const int MQ = CS * CB;   // 2048 rows
    for (int l = 0; l < CL; ++l) {
        const size_t wOff = (size_t)l * CD * CN * CDH;
        gemm_kernel<false, false><<<dim3(CD / 128, MQ / 128), 256, 0, stream>>>(
            cur, Wq + wOff, qh, MQ, CD, CD, nullptr, nullptr);
        gemm_kernel<false, false><<<dim3(CD / 128, MQ / 128), 256, 0, stream>>>(
            cur, Wk + wOff, kh, MQ, CD, CD, nullptr, nullptr);
        gemm_kernel<false, false><<<dim3(CD / 128, MQ / 128), 256, 0, stream>>>(
            cur, Wv + wOff, vh, MQ, CD, CD, nullptr, nullptr);
        gemm_kernel<false, false><<<dim3(CD / 128, (CR * CB) / 128), 256, 0, stream>>>(
            pos_emb, Wr + wOff, krb, CR * CB, CD, CD, nullptr, nullptr);
        ef_kernel<<<(CS * CB * CN) / 256, 256, 0, stream>>>(
            qh, rsb + (size_t)l * CN * CDH, sege + (size_t)l * 2 * CN * CDH, efb);
        attn_kernel<<<dim3(CS / 8, CB * CN), 256, 0, stream>>>(
            qh, kh, vh, krb, efb, segb,
            rwb + (size_t)l * CN * CDH, rrb + (size_t)l * CN * CDH, vec);
        gemm_kernel<true, false><<<dim3(CD / 128, MQ / 128), 256, 0, stream>>>(
            vec, Wo + wOff, ax, MQ, CD, CD, nullptr, cur);
        ln_kernel<<<MQ, 256, 0, stream>>>(ax, xb, ln1g + l * CD, ln1b + l * CD);
        gemm_kernel<false, true><<<dim3(CDI / 128, MQ / 128), 256, 0, stream>>>(
            xb, fw1 + (size_t)l * CD * CDI, ff, MQ, CDI, CD, fb1 + l * CDI, nullptr);
        gemm_kernel<false, false><<<dim3(CD / 128, MQ / 128), 256, 0, stream>>>(
            ff, fw2 + (size_t)l * CDI * CD, ax, MQ, CD, CDI, fb2 + l * CD, xb);
        ln_kernel<<<MQ, 256, 0, stream>>>(
            ax, (l == CL - 1) ? out : cur, ln2g + l * CD, ln2b + l * CD);
    }
}

// Round 2
// 2515.396 us; speedup vs baseline: 2.2136x; 2.2136x over previous
//
#include <hip/hip_runtime.h>
#include <hip/hip_bf16.h>
#include <math.h>

#define CS  1024
#define CB  2
#define CD  1024
#define CN  16
#define CDH 64
#define CDI 4096
#define CR  2048
#define CL  2

typedef __bf16 bf16x8 __attribute__((ext_vector_type(8)));
typedef float  f32x4  __attribute__((ext_vector_type(4)));

__device__ __forceinline__ unsigned short f2b(float f) {
    unsigned int u = __float_as_uint(f);
    u += 0x7FFF + ((u >> 16) & 1);          // RNE
    return (unsigned short)(u >> 16);
}

// ---------------------------------------------------------------------------
// flat fp32 -> bf16 convert (x4 vectorized), n4 = count/4
// ---------------------------------------------------------------------------
__global__ __launch_bounds__(256) void convert_f2b_kernel(
    const float* __restrict__ in, unsigned short* __restrict__ out, int n4)
{
    const int i = blockIdx.x * 256 + threadIdx.x;
    if (i >= n4) return;
    const float4 v = ((const float4*)in)[i];
    ushort4 o;
    o.x = f2b(v.x); o.y = f2b(v.y); o.z = f2b(v.z); o.w = f2b(v.w);
    ((ushort4*)out)[i] = o;
}

// ---------------------------------------------------------------------------
// fp32 [K,N] -> bf16 [N,K] transpose-convert, 32x32 LDS tiles
// ---------------------------------------------------------------------------
__global__ __launch_bounds__(256) void transpose_f2b_kernel(
    const float* __restrict__ in, unsigned short* __restrict__ out, int K, int N)
{
    __shared__ unsigned short t[32][33];
    const int k0 = blockIdx.y * 32, n0 = blockIdx.x * 32;
    const int c = threadIdx.x & 31, r0 = threadIdx.x >> 5;
    for (int r = r0; r < 32; r += 8)
        t[r][c] = f2b(in[(size_t)(k0 + r) * N + n0 + c]);
    __syncthreads();
    for (int r = r0; r < 32; r += 8)
        out[(size_t)(n0 + r) * K + k0 + c] = t[c][r];
}

// ---------------------------------------------------------------------------
// bf16 MFMA GEMM: C[M,N] = A[M,K] @ Bt[N,K]^T   (m93-style, 16x16x32 bf16)
// Tile (32*FM)x(32*FN), 256 thr = 4 waves in 2x2, wave tile 16*FM x 16*FN.
// LDS rows stride 40 bf16 (80 B): conflict-free ds_read_b128 frag loads.
// EPI bits: 1=bias  2=gelu(exact)  4=res add  8=bf16 out  16=split3 out
// ---------------------------------------------------------------------------
template<int FM, int FN, int EPI>
__global__ __launch_bounds__(256) void mgemm(
    const __bf16* __restrict__ A, const __bf16* __restrict__ Bt,
    float* __restrict__ C0, float* __restrict__ C1, float* __restrict__ C2,
    __bf16* __restrict__ Cb, int M, int N, int K,
    const float* __restrict__ bias, const float* __restrict__ res)
{
    constexpr int TM = 32 * FM, TN = 32 * FN;
    __shared__ __align__(16) __bf16 As[TM * 40];
    __shared__ __align__(16) __bf16 Bs[TN * 40];
    const int tid  = threadIdx.x;
    const int wave = tid >> 6, lane = tid & 63;
    const int q = lane >> 4, p = lane & 15;
    const int m0 = blockIdx.y * TM, n0 = blockIdx.x * TN;
    const int wm = (wave & 1) * (16 * FM);
    const int wn = (wave >> 1) * (16 * FN);

    f32x4 acc[FM][FN];
#pragma unroll
    for (int i = 0; i < FM; ++i)
#pragma unroll
        for (int j = 0; j < FN; ++j) {
            acc[i][j][0] = 0.f; acc[i][j][1] = 0.f;
            acc[i][j][2] = 0.f; acc[i][j][3] = 0.f;
        }

    for (int k0 = 0; k0 < K; k0 += 32) {
#pragma unroll
        for (int it = 0; it < TM / 64; ++it) {
            const int e = it * 256 + tid;
            const int r = e >> 2, cb = (e & 3) << 3;
            *(uint4*)(As + r * 40 + cb) =
                *(const uint4*)(A + (size_t)(m0 + r) * K + (k0 + cb));
        }
#pragma unroll
        for (int it = 0; it < TN / 64; ++it) {
            const int e = it * 256 + tid;
            const int r = e >> 2, cb = (e & 3) << 3;
            *(uint4*)(Bs + r * 40 + cb) =
                *(const uint4*)(Bt + (size_t)(n0 + r) * K + (k0 + cb));
        }
        __syncthreads();
        bf16x8 af[FM], bfr[FN];
#pragma unroll
        for (int i = 0; i < FM; ++i)
            af[i] = *(const bf16x8*)(As + (wm + i * 16 + p) * 40 + q * 8);
#pragma unroll
        for (int j = 0; j < FN; ++j)
            bfr[j] = *(const bf16x8*)(Bs + (wn + j * 16 + p) * 40 + q * 8);
#pragma unroll
        for (int i = 0; i < FM; ++i)
#pragma unroll
            for (int j = 0; j < FN; ++j)
                acc[i][j] = __builtin_amdgcn_mfma_f32_16x16x32_bf16(
                    af[i], bfr[j], acc[i][j], 0, 0, 0);
        __syncthreads();
    }

    // C/D layout: col = lane&15, row = (lane>>4)*4 + reg   [verified m89/m91]
#pragma unroll
    for (int i = 0; i < FM; ++i) {
#pragma unroll
        for (int j = 0; j < FN; ++j) {
            const int col = n0 + wn + j * 16 + p;
            const float bv = (EPI & 1) ? bias[col] : 0.0f;
#pragma unroll
            for (int r = 0; r < 4; ++r) {
                const int row = m0 + wm + i * 16 + q * 4 + r;
                float v = acc[i][j][r] + bv;
                if (EPI & 2) v = 0.5f * v * (1.0f + erff(v * 0.70710678118654752f));
                if (EPI & 4) v += res[(size_t)row * N + col];
                if (EPI & 16) {
                    float* dst = (col < 1024) ? C0 : (col < 2048 ? C1 : C2);
                    dst[(size_t)row * 1024 + (col & 1023)] = v;
                } else if (EPI & 8) {
                    Cb[(size_t)row * N + col] = (__bf16)v;
                } else {
                    C0[(size_t)row * N + col] = v;
                }
            }
        }
    }
}

// ---------------------------------------------------------------------------
// Pack seg_mat[S,S,B,2] one-hot into byte array segb[b][i][j]
// ---------------------------------------------------------------------------
__global__ __launch_bounds__(256) void segpack_kernel(
    const float* __restrict__ seg_mat, unsigned char* __restrict__ segb)
{
    const int idx = blockIdx.x * 256 + threadIdx.x;
    const int b   = idx / (CS * CS);
    const int rem = idx - b * (CS * CS);
    const int i   = rem >> 10;
    const int j   = rem & (CS - 1);
    segb[idx] = seg_mat[(((size_t)i * CS + j) * CB + b) * 2 + 1] > 0.5f ? 1 : 0;
}

// ---------------------------------------------------------------------------
// ef[s][i,b,n] = sum_d (qh + r_s_bias) * seg_embed[s]
// ---------------------------------------------------------------------------
__global__ __launch_bounds__(256) void ef_kernel(
    const float* __restrict__ qh, const float* __restrict__ rsb,
    const float* __restrict__ sege, float* __restrict__ ef)
{
    const int idx = blockIdx.x * 256 + threadIdx.x;
    const int n = idx & (CN - 1);
    const float* qp = qh + (size_t)idx * CDH;
    const float* sb = rsb + n * CDH;
    const float* s0 = sege + n * CDH;
    const float* s1 = sege + (CN + n) * CDH;
    float e0 = 0.f, e1 = 0.f;
#pragma unroll
    for (int d = 0; d < CDH; ++d) {
        const float qv = qp[d] + sb[d];
        e0 = fmaf(qv, s0[d], e0);
        e1 = fmaf(qv, s1[d], e1);
    }
    ef[idx] = e0;
    ef[CS * CB * CN + idx] = e1;
}

// ---------------------------------------------------------------------------
// Relative attention (fp32, unchanged from verified R1 kernel)
// ---------------------------------------------------------------------------
__global__ __launch_bounds__(256) void attn_kernel(
    const float* __restrict__ qh, const float* __restrict__ kh,
    const float* __restrict__ vh, const float* __restrict__ kr,
    const float* __restrict__ ef, const unsigned char* __restrict__ segb,
    const float* __restrict__ rwb, const float* __restrict__ rrb,
    float* __restrict__ vec)
{
    __shared__ float sc[8][CS];
    __shared__ float kt[32 * 65];
    __shared__ float krt[40 * 65];
    __shared__ float qrw[8][64];
    __shared__ float qrr[8][64];
    __shared__ float ef0s[8], ef1s[8], rinv[8];

    const int i0 = blockIdx.x * 8;
    const int b  = blockIdx.y >> 4;
    const int n  = blockIdx.y & 15;
    const int tid = threadIdx.x;
    const int r = tid >> 5;
    const int c = tid & 31;

    for (int idx = tid; idx < 512; idx += 256) {
        const int rr = idx >> 6, d = idx & 63;
        const float qv = qh[(((size_t)(i0 + rr) * CB + b) * CN + n) * CDH + d];
        qrw[rr][d] = qv + rwb[n * CDH + d];
        qrr[rr][d] = qv + rrb[n * CDH + d];
    }
    if (tid < 8) {
        const size_t e = ((size_t)(i0 + tid) * CB + b) * CN + n;
        ef0s[tid] = ef[e];
        ef1s[tid] = ef[(size_t)CS * CB * CN + e];
    }
    __syncthreads();

    const int ntile = (i0 + 8 + 31) >> 5;
    const int i = i0 + r;

    for (int t = 0; t < ntile; ++t) {
        const int j0 = t << 5;
        for (int idx = tid; idx < 2048; idx += 256) {
            const int row = idx >> 6, d = idx & 63;
            kt[row * 65 + d] = kh[(((size_t)(j0 + row) * CB + b) * CN + n) * CDH + d];
        }
        const int gbase = j0 + CS - i0 - 7;
        for (int idx = tid; idx < 2560; idx += 256) {
            const int row = idx >> 6, d = idx & 63;
            const int g = gbase + row;
            krt[row * 65 + d] = (g >= 0 && g < CR)
                ? kr[(((size_t)g * CB + b) * CN + n) * CDH + d] : 0.f;
        }
        __syncthreads();
        const int j = j0 + c;
        float s = -1e30f;
        if (j <= i) {
            const float* kk = &kt[c * 65];
            const float* kg = &krt[(c + 7 - r) * 65];
            float s1 = 0.f, s2 = 0.f;
#pragma unroll
            for (int d = 0; d < 64; ++d) {
                s1 = fmaf(qrw[r][d], kk[d], s1);
                s2 = fmaf(qrr[r][d], kg[d], s2);
            }
            const float e = segb[((size_t)b * CS + i) * CS + j] ? ef1s[r] : ef0s[r];
            s = (s1 + s2 + e) * 0.125f;
        }
        sc[r][j] = s;
        __syncthreads();
    }

    const int JV = ntile << 5;
    float m = -1e30f;
    for (int jj = c; jj < JV; jj += 32) m = fmaxf(m, sc[r][jj]);
#pragma unroll
    for (int off = 16; off; off >>= 1) m = fmaxf(m, __shfl_xor(m, off, 32));
    float ssum = 0.f;
    for (int jj = c; jj < JV; jj += 32) {
        const float pw = __expf(sc[r][jj] - m);
        sc[r][jj] = pw;
        ssum += pw;
    }
#pragma unroll
    for (int off = 16; off; off >>= 1) ssum += __shfl_xor(ssum, off, 32);
    if (c == 0) rinv[r] = 1.f / ssum;
    __syncthreads();

    float o0 = 0.f, o1 = 0.f;
    for (int t = 0; t < ntile; ++t) {
        const int j0 = t << 5;
        for (int idx = tid; idx < 2048; idx += 256) {
            const int row = idx >> 6, d = idx & 63;
            kt[row * 65 + d] = vh[(((size_t)(j0 + row) * CB + b) * CN + n) * CDH + d];
        }
        __syncthreads();
#pragma unroll
        for (int jj = 0; jj < 32; ++jj) {
            const float pw = sc[r][j0 + jj];
            o0 = fmaf(pw, kt[jj * 65 + c], o0);
            o1 = fmaf(pw, kt[jj * 65 + c + 32], o1);
        }
        __syncthreads();
    }
    const float ri = rinv[r];
    float* op = vec + (((size_t)i * CB + b) * CN + n) * CDH;
    op[c]      = o0 * ri;
    op[c + 32] = o1 * ri;
}

// ---------------------------------------------------------------------------
// LayerNorm over D=1024
// ---------------------------------------------------------------------------
__global__ __launch_bounds__(256) void ln_kernel(
    const float* __restrict__ x, float* __restrict__ y,
    const float* __restrict__ g, const float* __restrict__ bb)
{
    __shared__ float red[8];
    const int row = blockIdx.x;
    const int tid = threadIdx.x;
    const float4 v = ((const float4*)(x + (size_t)row * CD))[tid];
    float s = v.x + v.y + v.z + v.w;
#pragma unroll
    for (int off = 32; off; off >>= 1) s += __shfl_xor(s, off, 64);
    if ((tid & 63) == 0) red[tid >> 6] = s;
    __syncthreads();
    const float mean = (red[0] + red[1] + red[2] + red[3]) * (1.f / CD);
    const float d0 = v.x - mean, d1 = v.y - mean, d2 = v.z - mean, d3 = v.w - mean;
    float ss = d0 * d0 + d1 * d1 + d2 * d2 + d3 * d3;
#pragma unroll
    for (int off = 32; off; off >>= 1) ss += __shfl_xor(ss, off, 64);
    if ((tid & 63) == 0) red[4 + (tid >> 6)] = ss;
    __syncthreads();
    const float var  = (red[4] + red[5] + red[6] + red[7]) * (1.f / CD);
    const float rstd = rsqrtf(var + 1e-12f);
    const float4 gv = ((const float4*)g)[tid];
    const float4 bv = ((const float4*)bb)[tid];
    float4 o;
    o.x = d0 * rstd * gv.x + bv.x;
    o.y = d1 * rstd * gv.y + bv.y;
    o.z = d2 * rstd * gv.z + bv.z;
    o.w = d3 * rstd * gv.w + bv.w;
    ((float4*)(y + (size_t)row * CD))[tid] = o;
}

// ---------------------------------------------------------------------------
// Orchestration. Workspace byte layout (MiB):
//   0-8 cur | 8-16 qh | 16-24 kh | 24-32 vh | 32-48 krb | 48-56 vec
//   56-64 xb | 64-72 wbuf(bf16 weights) | 72-72.25 ef | 72.25-74.25 segb
// Aliases (stream-ordered lifetimes):
//   cur_b @32 (dead after QKV, before R writes krb) | pos_b @56 (dead at ln1)
//   ff bf16 @8-24 (qh/kh dead post-attn) | xb_b @32, vec_b @36 (krb dead)
//   ax @48 (vec dead once vec_b made)
// ---------------------------------------------------------------------------
extern "C" void kernel_launch(void* const* d_in, const int* in_sizes, int n_in,
                              void* d_out, int out_size, void* d_ws, size_t ws_size,
                              hipStream_t stream)
{
    const float* h       = (const float*)d_in[0];
    const float* pos_emb = (const float*)d_in[1];
    const float* seg_mat = (const float*)d_in[3];
    const float* Wq  = (const float*)d_in[4];
    const float* Wk  = (const float*)d_in[5];
    const float* Wv  = (const float*)d_in[6];
    const float* Wo  = (const float*)d_in[7];
    const float* Wr  = (const float*)d_in[8];
    const float* rwb = (const float*)d_in[9];
    const float* rrb = (const float*)d_in[10];
    const float* rsb = (const float*)d_in[11];
    const float* sege = (const float*)d_in[12];
    const float* ln1g = (const float*)d_in[13];
    const float* ln1b = (const float*)d_in[14];
    const float* fw1  = (const float*)d_in[15];
    const float* fb1  = (const float*)d_in[16];
    const float* fw2  = (const float*)d_in[17];
    const float* fb2  = (const float*)d_in[18];
    const float* ln2g = (const float*)d_in[19];
    const float* ln2b = (const float*)d_in[20];
    float* out = (float*)d_out;

    char* base = (char*)d_ws;
    const size_t MB = 1u << 20;
    float* cur  = (float*)(base + 0 * MB);
    float* qh   = (float*)(base + 8 * MB);
    float* kh   = (float*)(base + 16 * MB);
    float* vh   = (float*)(base + 24 * MB);
    float* krb  = (float*)(base + 32 * MB);
    float* vec  = (float*)(base + 48 * MB);
    float* xb   = (float*)(base + 56 * MB);
    unsigned short* wbuf = (unsigned short*)(base + 64 * MB);
    float* efb  = (float*)(base + 72 * MB);
    unsigned char* segb = (unsigned char*)(base + 72 * MB + (1u << 18));
    // aliases
    unsigned short* cur_b = (unsigned short*)(base + 32 * MB);
    unsigned short* pos_b = (unsigned short*)(base + 56 * MB);
    unsigned short* xb_b  = (unsigned short*)(base + 32 * MB);
    unsigned short* vec_b = (unsigned short*)(base + 36 * MB);
    float*  ax  = (float*)(base + 48 * MB);
    __bf16* ffb = (__bf16*)(base + 8 * MB);

    hipMemcpyAsync(cur, h, (size_t)CS * CB * CD * sizeof(float),
                   hipMemcpyDeviceToDevice, stream);
    segpack_kernel<<<(CS * CS * CB) / 256, 256, 0, stream>>>(seg_mat, segb);

    const int MQ = CS * CB;   // 2048
    for (int l = 0; l < CL; ++l) {
        const size_t wOff = (size_t)l * CD * CN * CDH;
        // bf16 conversions for this layer's GEMM inputs
        convert_f2b_kernel<<<(MQ * CD / 4 + 255) / 256, 256, 0, stream>>>(cur, cur_b, MQ * CD / 4);
        convert_f2b_kernel<<<(CR * CB * CD / 4 + 255) / 256, 256, 0, stream>>>(
            pos_emb, pos_b, CR * CB * CD / 4);
        // fused QKV: Bt = [WqT ; WkT ; WvT]  (3072 x 1024)
        transpose_f2b_kernel<<<dim3(32, 32), 256, 0, stream>>>(Wq + wOff, wbuf, CD, CD);
        transpose_f2b_kernel<<<dim3(32, 32), 256, 0, stream>>>(Wk + wOff, wbuf + 1024 * 1024, CD, CD);
        transpose_f2b_kernel<<<dim3(32, 32), 256, 0, stream>>>(Wv + wOff, wbuf + 2 * 1024 * 1024, CD, CD);
        mgemm<4, 4, 16><<<dim3(3072 / 128, MQ / 128), 256, 0, stream>>>(
            (const __bf16*)cur_b, (const __bf16*)wbuf, qh, kh, vh, nullptr,
            MQ, 3072, CD, nullptr, nullptr);
        // R projection: krb[4096,1024]
        transpose_f2b_kernel<<<dim3(32, 32), 256, 0, stream>>>(Wr + wOff, wbuf, CD, CD);
        mgemm<2, 4, 0><<<dim3(1024 / 128, (CR * CB) / 64), 256, 0, stream>>>(
            (const __bf16*)pos_b, (const __bf16*)wbuf, krb, nullptr, nullptr, nullptr,
            CR * CB, CD, CD, nullptr, nullptr);
        // segment scores + attention (fp32)
        ef_kernel<<<(CS * CB * CN) / 256, 256, 0, stream>>>(
            qh, rsb + (size_t)l * CN * CDH, sege + (size_t)l * 2 * CN * CDH, efb);
        attn_kernel<<<dim3(CS / 8, CB * CN), 256, 0, stream>>>(
            qh, kh, vh, krb, efb, segb,
            rwb + (size_t)l * CN * CDH, rrb + (size_t)l * CN * CDH, vec);
        // Wo projection + residual
        convert_f2b_kernel<<<(MQ * CD / 4 + 255) / 256, 256, 0, stream>>>(vec, vec_b, MQ * CD / 4);
        convert_f2b_kernel<<<(CD * CD / 4 + 255) / 256, 256, 0, stream>>>(Wo + wOff, wbuf, CD * CD / 4);
        mgemm<2, 4, 4><<<dim3(1024 / 128, MQ / 64), 256, 0, stream>>>(
            (const __bf16*)vec_b, (const __bf16*)wbuf, ax, nullptr, nullptr, nullptr,
            MQ, CD, CD, nullptr, cur);
        ln_kernel<<<MQ, 256, 0, stream>>>(ax, xb, ln1g + l * CD, ln1b + l * CD);
        // FFN
        convert_f2b_kernel<<<(MQ * CD / 4 + 255) / 256, 256, 0, stream>>>(xb, xb_b, MQ * CD / 4);
        transpose_f2b_kernel<<<dim3(CDI / 32, CD / 32), 256, 0, stream>>>(
            fw1 + (size_t)l * CD * CDI, wbuf, CD, CDI);
        mgemm<4, 4, 1 | 2 | 8><<<dim3(CDI / 128, MQ / 128), 256, 0, stream>>>(
            (const __bf16*)xb_b, (const __bf16*)wbuf, nullptr, nullptr, nullptr, ffb,
            MQ, CDI, CD, fb1 + l * CDI, nullptr);
        transpose_f2b_kernel<<<dim3(CD / 32, CDI / 32), 256, 0, stream>>>(
            fw2 + (size_t)l * CDI * CD, wbuf, CDI, CD);
        mgemm<2, 4, 1 | 4><<<dim3(CD / 128, MQ / 64), 256, 0, stream>>>(
            ffb, (const __bf16*)wbuf, ax, nullptr, nullptr, nullptr,
            MQ, CD, CDI, fb2 + l * CD, xb);
        ln_kernel<<<MQ, 256, 0, stream>>>(
            ax, (l == CL - 1) ? out : cur, ln2g + l * CD, ln2b + l * CD);
    }
}

// Round 3
// 861.914 us; speedup vs baseline: 6.4603x; 2.9184x over previous
//
#include <hip/hip_runtime.h>
#include <hip/hip_bf16.h>
#include <math.h>

#define CS  1024
#define CB  2
#define CD  1024
#define CN  16
#define CDH 64
#define CDI 4096
#define CR  2048
#define CL  2

typedef __bf16 bf16x8 __attribute__((ext_vector_type(8)));
typedef float  f32x4  __attribute__((ext_vector_type(4)));

__device__ __forceinline__ unsigned short f2b(float f) {
    unsigned int u = __float_as_uint(f);
    u += 0x7FFF + ((u >> 16) & 1);          // RNE
    return (unsigned short)(u >> 16);
}

// ---------------------------------------------------------------------------
// flat fp32 -> bf16 convert (x4 vectorized), n4 = count/4
// ---------------------------------------------------------------------------
__global__ __launch_bounds__(256) void convert_f2b_kernel(
    const float* __restrict__ in, unsigned short* __restrict__ out, int n4)
{
    const int i = blockIdx.x * 256 + threadIdx.x;
    if (i >= n4) return;
    const float4 v = ((const float4*)in)[i];
    ushort4 o;
    o.x = f2b(v.x); o.y = f2b(v.y); o.z = f2b(v.z); o.w = f2b(v.w);
    ((ushort4*)out)[i] = o;
}

// ---------------------------------------------------------------------------
// fp32 [K,N] -> bf16 [N,K] transpose-convert, 32x32 LDS tiles
// ---------------------------------------------------------------------------
__global__ __launch_bounds__(256) void transpose_f2b_kernel(
    const float* __restrict__ in, unsigned short* __restrict__ out, int K, int N)
{
    __shared__ unsigned short t[32][33];
    const int k0 = blockIdx.y * 32, n0 = blockIdx.x * 32;
    const int c = threadIdx.x & 31, r0 = threadIdx.x >> 5;
    for (int r = r0; r < 32; r += 8)
        t[r][c] = f2b(in[(size_t)(k0 + r) * N + n0 + c]);
    __syncthreads();
    for (int r = r0; r < 32; r += 8)
        out[(size_t)(n0 + r) * K + k0 + c] = t[c][r];
}

// ---------------------------------------------------------------------------
// bf16 MFMA GEMM: C[M,N] = A[M,K] @ Bt[N,K]^T   (16x16x32 bf16)
// EPI bits: 1=bias  2=gelu(exact)  4=res add  8=bf16 out  16=split3 out
// ---------------------------------------------------------------------------
template<int FM, int FN, int EPI>
__global__ __launch_bounds__(256) void mgemm(
    const __bf16* __restrict__ A, const __bf16* __restrict__ Bt,
    float* __restrict__ C0, float* __restrict__ C1, float* __restrict__ C2,
    __bf16* __restrict__ Cb, int M, int N, int K,
    const float* __restrict__ bias, const float* __restrict__ res)
{
    constexpr int TM = 32 * FM, TN = 32 * FN;
    __shared__ __align__(16) __bf16 As[TM * 40];
    __shared__ __align__(16) __bf16 Bs[TN * 40];
    const int tid  = threadIdx.x;
    const int wave = tid >> 6, lane = tid & 63;
    const int q = lane >> 4, p = lane & 15;
    const int m0 = blockIdx.y * TM, n0 = blockIdx.x * TN;
    const int wm = (wave & 1) * (16 * FM);
    const int wn = (wave >> 1) * (16 * FN);

    f32x4 acc[FM][FN];
#pragma unroll
    for (int i = 0; i < FM; ++i)
#pragma unroll
        for (int j = 0; j < FN; ++j) {
            acc[i][j][0] = 0.f; acc[i][j][1] = 0.f;
            acc[i][j][2] = 0.f; acc[i][j][3] = 0.f;
        }

    for (int k0 = 0; k0 < K; k0 += 32) {
#pragma unroll
        for (int it = 0; it < TM / 64; ++it) {
            const int e = it * 256 + tid;
            const int r = e >> 2, cb = (e & 3) << 3;
            *(uint4*)(As + r * 40 + cb) =
                *(const uint4*)(A + (size_t)(m0 + r) * K + (k0 + cb));
        }
#pragma unroll
        for (int it = 0; it < TN / 64; ++it) {
            const int e = it * 256 + tid;
            const int r = e >> 2, cb = (e & 3) << 3;
            *(uint4*)(Bs + r * 40 + cb) =
                *(const uint4*)(Bt + (size_t)(n0 + r) * K + (k0 + cb));
        }
        __syncthreads();
        bf16x8 af[FM], bfr[FN];
#pragma unroll
        for (int i = 0; i < FM; ++i)
            af[i] = *(const bf16x8*)(As + (wm + i * 16 + p) * 40 + q * 8);
#pragma unroll
        for (int j = 0; j < FN; ++j)
            bfr[j] = *(const bf16x8*)(Bs + (wn + j * 16 + p) * 40 + q * 8);
#pragma unroll
        for (int i = 0; i < FM; ++i)
#pragma unroll
            for (int j = 0; j < FN; ++j)
                acc[i][j] = __builtin_amdgcn_mfma_f32_16x16x32_bf16(
                    af[i], bfr[j], acc[i][j], 0, 0, 0);
        __syncthreads();
    }

#pragma unroll
    for (int i = 0; i < FM; ++i) {
#pragma unroll
        for (int j = 0; j < FN; ++j) {
            const int col = n0 + wn + j * 16 + p;
            const float bv = (EPI & 1) ? bias[col] : 0.0f;
#pragma unroll
            for (int r = 0; r < 4; ++r) {
                const int row = m0 + wm + i * 16 + q * 4 + r;
                float v = acc[i][j][r] + bv;
                if (EPI & 2) v = 0.5f * v * (1.0f + erff(v * 0.70710678118654752f));
                if (EPI & 4) v += res[(size_t)row * N + col];
                if (EPI & 16) {
                    float* dst = (col < 1024) ? C0 : (col < 2048 ? C1 : C2);
                    dst[(size_t)row * 1024 + (col & 1023)] = v;
                } else if (EPI & 8) {
                    Cb[(size_t)row * N + col] = (__bf16)v;
                } else {
                    C0[(size_t)row * N + col] = v;
                }
            }
        }
    }
}

// ---------------------------------------------------------------------------
// Pack seg_mat[S,S,B,2] one-hot into byte array segb[b][i][j]
// ---------------------------------------------------------------------------
__global__ __launch_bounds__(256) void segpack_kernel(
    const float* __restrict__ seg_mat, unsigned char* __restrict__ segb)
{
    const int idx = blockIdx.x * 256 + threadIdx.x;
    const int b   = idx / (CS * CS);
    const int rem = idx - b * (CS * CS);
    const int i   = rem >> 10;
    const int j   = rem & (CS - 1);
    segb[idx] = seg_mat[(((size_t)i * CS + j) * CB + b) * 2 + 1] > 0.5f ? 1 : 0;
}

// ---------------------------------------------------------------------------
// ef[s][i,b,n] = sum_d (qh + r_s_bias) * seg_embed[s]
// ---------------------------------------------------------------------------
__global__ __launch_bounds__(256) void ef_kernel(
    const float* __restrict__ qh, const float* __restrict__ rsb,
    const float* __restrict__ sege, float* __restrict__ ef)
{
    const int idx = blockIdx.x * 256 + threadIdx.x;
    const int n = idx & (CN - 1);
    const float* qp = qh + (size_t)idx * CDH;
    const float* sb = rsb + n * CDH;
    const float* s0 = sege + n * CDH;
    const float* s1 = sege + (CN + n) * CDH;
    float e0 = 0.f, e1 = 0.f;
#pragma unroll
    for (int d = 0; d < CDH; ++d) {
        const float qv = qp[d] + sb[d];
        e0 = fmaf(qv, s0[d], e0);
        e1 = fmaf(qv, s1[d], e1);
    }
    ef[idx] = e0;
    ef[CS * CB * CN + idx] = e1;
}

// ---------------------------------------------------------------------------
// MFMA flash attention with rel-shift + segment bias.
// Block = (i-tile of 64 rows, b, n). 4 waves, 16 q-rows each.
// LDS strides (bf16 units): K/Kr 40, Vt 48, P 72, raw 83.
// ---------------------------------------------------------------------------
#define KSTR 40
#define VSTR 48
#define PSTR 72
#define RSTR 83

__global__ __launch_bounds__(256) void attn_mfma_kernel(
    const float* __restrict__ qh, const float* __restrict__ kh,
    const float* __restrict__ vh, const float* __restrict__ kr,
    const float* __restrict__ efb, const unsigned char* __restrict__ segb,
    const float* __restrict__ rwb, const float* __restrict__ rrb,
    float* __restrict__ vec)
{
    __shared__ __align__(16) char smem[62848];
    __bf16* raww = (__bf16*)(smem);            // [4][16][RSTR]  10624 B
    __bf16* Pl   = (__bf16*)(smem + 10624);    // [4][16][PSTR]   9216 B
    __bf16* Ks   = (__bf16*)(smem + 19840);    // [2][64][KSTR]  10240 B
    __bf16* Vt   = (__bf16*)(smem + 30080);    // [2][64][VSTR]  12288 B
    __bf16* Krs  = (__bf16*)(smem + 42368);    // [2][128][KSTR] 20480 B

    const int i0 = blockIdx.x * 64;
    const int b  = blockIdx.y >> 4;
    const int n  = blockIdx.y & 15;
    const int tid = threadIdx.x;
    const int w = tid >> 6;
    const int lane = tid & 63;
    const int p = lane & 15, q = lane >> 4;

    // ---- persistent Q fragments (A-layout), bias added, direct from global
    bf16x8 qwF[2], qrF[2];
    {
        const float* qrow = qh + (((size_t)(i0 + 16 * w + p) * CB + b) * CN + n) * CDH;
        const float* rw = rwb + n * CDH;
        const float* rr = rrb + n * CDH;
#pragma unroll
        for (int ks = 0; ks < 2; ++ks)
#pragma unroll
            for (int t = 0; t < 8; ++t) {
                const int d = ks * 32 + q * 8 + t;
                const float v = qrow[d];
                qwF[ks][t] = (__bf16)(v + rw[d]);
                qrF[ks][t] = (__bf16)(v + rr[d]);
            }
    }
    // ---- ef values for this lane's 4 rows
    float ef0r[4], ef1r[4];
#pragma unroll
    for (int r = 0; r < 4; ++r) {
        const size_t e = ((size_t)(i0 + 16 * w + 4 * q + r) * CB + b) * CN + n;
        ef0r[r] = efb[e];
        ef1r[r] = efb[(size_t)CS * CB * CN + e];
    }

    f32x4 opv[4];
    float mrow[4], lrow[4];
#pragma unroll
    for (int nf = 0; nf < 4; ++nf) { opv[nf][0]=0.f; opv[nf][1]=0.f; opv[nf][2]=0.f; opv[nf][3]=0.f; }
#pragma unroll
    for (int r = 0; r < 4; ++r) { mrow[r] = -3.0e38f; lrow[r] = 0.f; }

    const int ntile = blockIdx.x + 1;
    const unsigned char* sb = segb + (size_t)b * CS * CS;
    const int wbase = 48 - 16 * w;

    for (int jt = 0; jt < ntile; ++jt) {
        const int j0 = jt * 64;
        const int gs = j0 + CS - i0 - 63;      // Kr band start, in [1, 961]

        // ---- stage K (64 rows), Kr (128 rows), V^T ----
#pragma unroll
        for (int it = 0; it < 2; ++it) {
            const int idx = it * 256 + tid;
            const int row = idx >> 3, oc = (idx & 7) * 8;
            const float* src = kh + (((size_t)(j0 + row) * CB + b) * CN + n) * CDH + oc;
            __bf16 tmp[8];
#pragma unroll
            for (int t = 0; t < 8; ++t) tmp[t] = (__bf16)src[t];
            *(uint4*)(Ks + (oc >> 5) * (64 * KSTR) + row * KSTR + (oc & 31)) = *(uint4*)tmp;
        }
#pragma unroll
        for (int it = 0; it < 4; ++it) {
            const int idx = it * 256 + tid;
            const int row = idx >> 3, oc = (idx & 7) * 8;
            const float* src = kr + (((size_t)(gs + row) * CB + b) * CN + n) * CDH + oc;
            __bf16 tmp[8];
#pragma unroll
            for (int t = 0; t < 8; ++t) tmp[t] = (__bf16)src[t];
            *(uint4*)(Krs + (oc >> 5) * (128 * KSTR) + row * KSTR + (oc & 31)) = *(uint4*)tmp;
        }
        {   // V transpose: lane handles j-pair x dh-octet; staggered t vs bank
            const int jp = tid >> 3, oc = (tid & 7) * 8;
            const int j = jp * 2, oct = oc >> 3;
            const float* s0 = vh + (((size_t)(j0 + j) * CB + b) * CN + n) * CDH + oc;
            const float* s1 = s0 + CB * CN * CDH;
            const int jh = j >> 5, jc = j & 31;
#pragma unroll
            for (int tt = 0; tt < 8; ++tt) {
                const int t = (tt + oct) & 7;
                const unsigned int dw = (unsigned int)f2b(s0[t]) |
                                        ((unsigned int)f2b(s1[t]) << 16);
                *(unsigned int*)(Vt + jh * (64 * VSTR) + (oc + t) * VSTR + jc) = dw;
            }
        }
        __syncthreads();

        // ---- scores: ac (8 MFMA) + bd raw band window (10 MFMA) ----
        f32x4 ac[4], rawacc[5];
#pragma unroll
        for (int nf = 0; nf < 4; ++nf) { ac[nf][0]=0.f; ac[nf][1]=0.f; ac[nf][2]=0.f; ac[nf][3]=0.f; }
#pragma unroll
        for (int t = 0; t < 5; ++t) { rawacc[t][0]=0.f; rawacc[t][1]=0.f; rawacc[t][2]=0.f; rawacc[t][3]=0.f; }
#pragma unroll
        for (int ks = 0; ks < 2; ++ks) {
#pragma unroll
            for (int nf = 0; nf < 4; ++nf) {
                const bf16x8 bf = *(const bf16x8*)(Ks + ks * (64 * KSTR) + (nf * 16 + p) * KSTR + q * 8);
                ac[nf] = __builtin_amdgcn_mfma_f32_16x16x32_bf16(qwF[ks], bf, ac[nf], 0, 0, 0);
            }
#pragma unroll
            for (int t = 0; t < 5; ++t) {
                const bf16x8 bf = *(const bf16x8*)(Krs + ks * (128 * KSTR) + (wbase + t * 16 + p) * KSTR + q * 8);
                rawacc[t] = __builtin_amdgcn_mfma_f32_16x16x32_bf16(qrF[ks], bf, rawacc[t], 0, 0, 0);
            }
        }
        // ---- write raw window to per-wave LDS (bf16) ----
        __bf16* rwl = raww + w * (16 * RSTR);
#pragma unroll
        for (int t = 0; t < 5; ++t)
#pragma unroll
            for (int r = 0; r < 4; ++r)
                rwl[(4 * q + r) * RSTR + t * 16 + p] = (__bf16)rawacc[t][r];

        // ---- extract shifted bd, add ef, mask, online softmax ----
        const bool diag = (jt == ntile - 1);
        float sc[4][4];
#pragma unroll
        for (int nf = 0; nf < 4; ++nf) {
            const int jj = nf * 16 + p;
#pragma unroll
            for (int r = 0; r < 4; ++r) {
                const int rl = 4 * q + r;
                const float bd = (float)rwl[rl * RSTR + (jj + 15 - rl)];
                const int ii = i0 + 16 * w + rl;
                const float e = sb[(size_t)ii * CS + (j0 + jj)] ? ef1r[r] : ef0r[r];
                float s = (ac[nf][r] + bd + e) * 0.125f;
                if (diag && jj > 16 * w + rl) s = -3.0e38f;
                sc[nf][r] = s;
            }
        }
        float mt[4], al[4], ls[4];
#pragma unroll
        for (int r = 0; r < 4; ++r) {
            float m = fmaxf(fmaxf(sc[0][r], sc[1][r]), fmaxf(sc[2][r], sc[3][r]));
#pragma unroll
            for (int off = 1; off < 16; off <<= 1) m = fmaxf(m, __shfl_xor(m, off));
            mt[r] = m;
            const float mn = fmaxf(mrow[r], mt[r]);
            al[r] = __expf(mrow[r] - mn);
            mrow[r] = mn;
            ls[r] = 0.f;
        }
#pragma unroll
        for (int nf = 0; nf < 4; ++nf)
#pragma unroll
            for (int r = 0; r < 4; ++r) {
                const float pv = __expf(sc[nf][r] - mrow[r]);
                sc[nf][r] = pv;
                ls[r] += pv;
            }
#pragma unroll
        for (int r = 0; r < 4; ++r) {
            float s = ls[r];
#pragma unroll
            for (int off = 1; off < 16; off <<= 1) s += __shfl_xor(s, off);
            lrow[r] = lrow[r] * al[r] + s;
#pragma unroll
            for (int nf = 0; nf < 4; ++nf) opv[nf][r] *= al[r];
        }
        // ---- P -> LDS (C-layout write), reread as A-layout ----
        __bf16* pw = Pl + w * (16 * PSTR);
#pragma unroll
        for (int nf = 0; nf < 4; ++nf)
#pragma unroll
            for (int r = 0; r < 4; ++r)
                pw[(4 * q + r) * PSTR + nf * 16 + p] = (__bf16)sc[nf][r];

#pragma unroll
        for (int ks = 0; ks < 2; ++ks) {
            const bf16x8 pf = *(const bf16x8*)(pw + p * PSTR + ks * 32 + q * 8);
#pragma unroll
            for (int nf = 0; nf < 4; ++nf) {
                const bf16x8 vf = *(const bf16x8*)(Vt + ks * (64 * VSTR) + (nf * 16 + p) * VSTR + q * 8);
                opv[nf] = __builtin_amdgcn_mfma_f32_16x16x32_bf16(pf, vf, opv[nf], 0, 0, 0);
            }
        }
        __syncthreads();
    }

    // ---- epilogue: normalize, write vec[i][b][n][dh]
#pragma unroll
    for (int r = 0; r < 4; ++r) {
        const float ri = 1.0f / lrow[r];
        const int i = i0 + 16 * w + 4 * q + r;
        float* op = vec + (((size_t)i * CB + b) * CN + n) * CDH;
#pragma unroll
        for (int nf = 0; nf < 4; ++nf)
            op[nf * 16 + p] = opv[nf][r] * ri;
    }
}

// ---------------------------------------------------------------------------
// LayerNorm over D=1024
// ---------------------------------------------------------------------------
__global__ __launch_bounds__(256) void ln_kernel(
    const float* __restrict__ x, float* __restrict__ y,
    const float* __restrict__ g, const float* __restrict__ bb)
{
    __shared__ float red[8];
    const int row = blockIdx.x;
    const int tid = threadIdx.x;
    const float4 v = ((const float4*)(x + (size_t)row * CD))[tid];
    float s = v.x + v.y + v.z + v.w;
#pragma unroll
    for (int off = 32; off; off >>= 1) s += __shfl_xor(s, off, 64);
    if ((tid & 63) == 0) red[tid >> 6] = s;
    __syncthreads();
    const float mean = (red[0] + red[1] + red[2] + red[3]) * (1.f / CD);
    const float d0 = v.x - mean, d1 = v.y - mean, d2 = v.z - mean, d3 = v.w - mean;
    float ss = d0 * d0 + d1 * d1 + d2 * d2 + d3 * d3;
#pragma unroll
    for (int off = 32; off; off >>= 1) ss += __shfl_xor(ss, off, 64);
    if ((tid & 63) == 0) red[4 + (tid >> 6)] = ss;
    __syncthreads();
    const float var  = (red[4] + red[5] + red[6] + red[7]) * (1.f / CD);
    const float rstd = rsqrtf(var + 1e-12f);
    const float4 gv = ((const float4*)g)[tid];
    const float4 bv = ((const float4*)bb)[tid];
    float4 o;
    o.x = d0 * rstd * gv.x + bv.x;
    o.y = d1 * rstd * gv.y + bv.y;
    o.z = d2 * rstd * gv.z + bv.z;
    o.w = d3 * rstd * gv.w + bv.w;
    ((float4*)(y + (size_t)row * CD))[tid] = o;
}

// ---------------------------------------------------------------------------
// Orchestration (workspace layout unchanged from R2, ~74.25 MiB proven)
// ---------------------------------------------------------------------------
extern "C" void kernel_launch(void* const* d_in, const int* in_sizes, int n_in,
                              void* d_out, int out_size, void* d_ws, size_t ws_size,
                              hipStream_t stream)
{
    const float* h       = (const float*)d_in[0];
    const float* pos_emb = (const float*)d_in[1];
    const float* seg_mat = (const float*)d_in[3];
    const float* Wq  = (const float*)d_in[4];
    const float* Wk  = (const float*)d_in[5];
    const float* Wv  = (const float*)d_in[6];
    const float* Wo  = (const float*)d_in[7];
    const float* Wr  = (const float*)d_in[8];
    const float* rwb = (const float*)d_in[9];
    const float* rrb = (const float*)d_in[10];
    const float* rsb = (const float*)d_in[11];
    const float* sege = (const float*)d_in[12];
    const float* ln1g = (const float*)d_in[13];
    const float* ln1b = (const float*)d_in[14];
    const float* fw1  = (const float*)d_in[15];
    const float* fb1  = (const float*)d_in[16];
    const float* fw2  = (const float*)d_in[17];
    const float* fb2  = (const float*)d_in[18];
    const float* ln2g = (const float*)d_in[19];
    const float* ln2b = (const float*)d_in[20];
    float* out = (float*)d_out;

    char* base = (char*)d_ws;
    const size_t MB = 1u << 20;
    float* cur  = (float*)(base + 0 * MB);
    float* qh   = (float*)(base + 8 * MB);
    float* kh   = (float*)(base + 16 * MB);
    float* vh   = (float*)(base + 24 * MB);
    float* krb  = (float*)(base + 32 * MB);
    float* vec  = (float*)(base + 48 * MB);
    float* xb   = (float*)(base + 56 * MB);
    unsigned short* wbuf = (unsigned short*)(base + 64 * MB);
    float* efb  = (float*)(base + 72 * MB);
    unsigned char* segb = (unsigned char*)(base + 72 * MB + (1u << 18));
    unsigned short* cur_b = (unsigned short*)(base + 32 * MB);
    unsigned short* pos_b = (unsigned short*)(base + 56 * MB);
    unsigned short* xb_b  = (unsigned short*)(base + 32 * MB);
    unsigned short* vec_b = (unsigned short*)(base + 36 * MB);
    float*  ax  = (float*)(base + 48 * MB);
    __bf16* ffb = (__bf16*)(base + 8 * MB);

    hipMemcpyAsync(cur, h, (size_t)CS * CB * CD * sizeof(float),
                   hipMemcpyDeviceToDevice, stream);
    segpack_kernel<<<(CS * CS * CB) / 256, 256, 0, stream>>>(seg_mat, segb);

    const int MQ = CS * CB;   // 2048
    for (int l = 0; l < CL; ++l) {
        const size_t wOff = (size_t)l * CD * CN * CDH;
        convert_f2b_kernel<<<(MQ * CD / 4 + 255) / 256, 256, 0, stream>>>(cur, cur_b, MQ * CD / 4);
        convert_f2b_kernel<<<(CR * CB * CD / 4 + 255) / 256, 256, 0, stream>>>(
            pos_emb, pos_b, CR * CB * CD / 4);
        transpose_f2b_kernel<<<dim3(32, 32), 256, 0, stream>>>(Wq + wOff, wbuf, CD, CD);
        transpose_f2b_kernel<<<dim3(32, 32), 256, 0, stream>>>(Wk + wOff, wbuf + 1024 * 1024, CD, CD);
        transpose_f2b_kernel<<<dim3(32, 32), 256, 0, stream>>>(Wv + wOff, wbuf + 2 * 1024 * 1024, CD, CD);
        mgemm<4, 4, 16><<<dim3(3072 / 128, MQ / 128), 256, 0, stream>>>(
            (const __bf16*)cur_b, (const __bf16*)wbuf, qh, kh, vh, nullptr,
            MQ, 3072, CD, nullptr, nullptr);
        transpose_f2b_kernel<<<dim3(32, 32), 256, 0, stream>>>(Wr + wOff, wbuf, CD, CD);
        mgemm<2, 4, 0><<<dim3(1024 / 128, (CR * CB) / 64), 256, 0, stream>>>(
            (const __bf16*)pos_b, (const __bf16*)wbuf, krb, nullptr, nullptr, nullptr,
            CR * CB, CD, CD, nullptr, nullptr);
        ef_kernel<<<(CS * CB * CN) / 256, 256, 0, stream>>>(
            qh, rsb + (size_t)l * CN * CDH, sege + (size_t)l * 2 * CN * CDH, efb);
        attn_mfma_kernel<<<dim3(CS / 64, CB * CN), 256, 0, stream>>>(
            qh, kh, vh, krb, efb, segb,
            rwb + (size_t)l * CN * CDH, rrb + (size_t)l * CN * CDH, vec);
        convert_f2b_kernel<<<(MQ * CD / 4 + 255) / 256, 256, 0, stream>>>(vec, vec_b, MQ * CD / 4);
        convert_f2b_kernel<<<(CD * CD / 4 + 255) / 256, 256, 0, stream>>>(Wo + wOff, wbuf, CD * CD / 4);
        mgemm<2, 4, 4><<<dim3(1024 / 128, MQ / 64), 256, 0, stream>>>(
            (const __bf16*)vec_b, (const __bf16*)wbuf, ax, nullptr, nullptr, nullptr,
            MQ, CD, CD, nullptr, cur);
        ln_kernel<<<MQ, 256, 0, stream>>>(ax, xb, ln1g + l * CD, ln1b + l * CD);
        convert_f2b_kernel<<<(MQ * CD / 4 + 255) / 256, 256, 0, stream>>>(xb, xb_b, MQ * CD / 4);
        transpose_f2b_kernel<<<dim3(CDI / 32, CD / 32), 256, 0, stream>>>(
            fw1 + (size_t)l * CD * CDI, wbuf, CD, CDI);
        mgemm<4, 4, 1 | 2 | 8><<<dim3(CDI / 128, MQ / 128), 256, 0, stream>>>(
            (const __bf16*)xb_b, (const __bf16*)wbuf, nullptr, nullptr, nullptr, ffb,
            MQ, CDI, CD, fb1 + l * CDI, nullptr);
        transpose_f2b_kernel<<<dim3(CD / 32, CDI / 32), 256, 0, stream>>>(
            fw2 + (size_t)l * CDI * CD, wbuf, CDI, CD);
        mgemm<2, 4, 1 | 4><<<dim3(CD / 128, MQ / 64), 256, 0, stream>>>(
            ffb, (const __bf16*)wbuf, ax, nullptr, nullptr, nullptr,
            MQ, CD, CDI, fb2 + l * CD, xb);
        ln_kernel<<<MQ, 256, 0, stream>>>(
            ax, (l == CL - 1) ? out : cur, ln2g + l * CD, ln2b + l * CD);
    }
}